// Round 1
// baseline (1164.133 us; speedup 1.0000x reference)
//
#include <hip/hip_runtime.h>
#include <cstdint>

#define NB 8
#define NBOX 8732
#define NCL 21
#define NCM1 20
#define LASTD 102
#define CONF_TH 0.5f
#define IOU_TH 0.45f
#define TOPK 200
#define MAXOUT 400
#define SORTN 8192
#define NTASK (NB * NCM1)

// IoU with explicit round-to-nearest ops (no FMA contraction) to match the
// host-side numpy/jax fp32 reference bit-for-bit. Strict > comparisons.
__device__ __forceinline__ bool iou_gt(float ax, float ay, float az, float aw,
                                       float bx, float by, float bz, float bw) {
    float x1 = fmaxf(ax, bx);
    float y1 = fmaxf(ay, by);
    float x2 = fminf(az, bz);
    float y2 = fminf(aw, bw);
    float iw = fmaxf(__fsub_rn(x2, x1), 0.0f);
    float ih = fmaxf(__fsub_rn(y2, y1), 0.0f);
    float inter = __fmul_rn(iw, ih);
    float aa = __fmul_rn(__fsub_rn(az, ax), __fsub_rn(aw, ay));
    float ab = __fmul_rn(__fsub_rn(bz, bx), __fsub_rn(bw, by));
    float uni = __fsub_rn(__fadd_rn(aa, ab), inter);
    if (!(uni > 0.0f)) return false;
    return __fdiv_rn(inter, uni) > IOU_TH;
}

// Descending bitonic sort of SORTN uint64 keys in LDS. 256 threads.
__device__ __forceinline__ void bitonic_sort_desc(uint64_t* keys, int tid) {
    for (int k = 2; k <= SORTN; k <<= 1) {
        for (int j = k >> 1; j > 0; j >>= 1) {
            for (int t = tid; t < SORTN; t += 256) {
                int ixj = t ^ j;
                if (ixj > t) {
                    uint64_t a = keys[t];
                    uint64_t c = keys[ixj];
                    bool up = ((t & k) == 0);
                    if (up ? (a < c) : (a > c)) {
                        keys[t] = c;
                        keys[ixj] = a;
                    }
                }
            }
            __syncthreads();
        }
    }
}

// One block per (image, class) task: compact conf>0.5 candidates, sort by
// (score desc, idx asc), greedy NMS scan (equivalent to the reference's
// 400-step argmax+suppress scan), emit 400 rows of 7 floats (zeros past nsel).
__global__ __launch_bounds__(256) void nms_per_class(const float* __restrict__ yp,
                                                     float* __restrict__ rows) {
    __shared__ uint64_t keys[SORTN];     // 64 KiB
    __shared__ float4 bbuf[256];         // 4 KiB: staged candidate boxes
    __shared__ float4 selbox[MAXOUT];    // 6.25 KiB
    __shared__ uint64_t selkey[MAXOUT];  // 3.125 KiB
    __shared__ int wsum[4];

    const int task = blockIdx.x;
    const int b = task / NCM1;
    const int cm1 = task % NCM1;
    const int tid = threadIdx.x;
    const int lane = tid & 63;
    const int wav = tid >> 6;
    const float* img = yp + (size_t)b * NBOX * LASTD;
    const int boxoff = NCL + 4 * cm1;

    // ---- phase 1: order-preserving compaction of conf>0.5 candidates ----
    int M = 0;
    for (int it = 0; it < (NBOX + 255) / 256; ++it) {
        int i = it * 256 + tid;
        float conf = 0.0f;
        bool pred = false;
        if (i < NBOX) {
            conf = img[(size_t)i * LASTD + (1 + cm1)];
            pred = conf > CONF_TH;
        }
        unsigned long long bal = __ballot(pred);
        int before = __popcll(bal & ((1ull << lane) - 1ull));
        if (lane == 0) wsum[wav] = __popcll(bal);
        __syncthreads();
        int wbase = 0;
        #pragma unroll
        for (int w = 0; w < 4; ++w)
            if (w < wav) wbase += wsum[w];
        int total = wsum[0] + wsum[1] + wsum[2] + wsum[3];
        if (pred) {
            int pos = M + wbase + before;
            if (pos < SORTN)
                keys[pos] = ((uint64_t)__float_as_uint(conf) << 32) |
                            (uint32_t)(0xFFFFFFFFu - (uint32_t)i);
        }
        M += total;
        __syncthreads();
    }
    if (M > SORTN) M = SORTN;
    for (int m = M + tid; m < SORTN; m += 256) keys[m] = 0;  // sentinel pad
    __syncthreads();

    // ---- phase 2: sort (score desc, original idx asc) ----
    bitonic_sort_desc(keys, tid);

    // ---- phase 3: greedy scan: accept unless IoU>0.45 vs an accepted box ----
    int nsel = 0;
    bool exhausted = false;
    for (int batch = 0; batch < SORTN / 256 && !exhausted && nsel < MAXOUT; ++batch) {
        // stage this batch's candidate boxes into LDS (parallel gather)
        {
            int m = batch * 256 + tid;
            uint64_t k0 = keys[m];
            if ((k0 >> 32) != 0) {
                uint32_t i = 0xFFFFFFFFu - (uint32_t)k0;
                const float* bp = img + (size_t)i * LASTD + boxoff;
                bbuf[tid] = make_float4(bp[0], bp[1], bp[2], bp[3]);
            }
        }
        __syncthreads();
        for (int t = 0; t < 256; ++t) {
            uint64_t key = keys[batch * 256 + t];  // uniform broadcast read
            if ((key >> 32) == 0) { exhausted = true; break; }
            float4 cb = bbuf[t];
            int sup = 0;
            for (int j = tid; j < nsel; j += 256) {
                float4 sb = selbox[j];
                if (iou_gt(cb.x, cb.y, cb.z, cb.w, sb.x, sb.y, sb.z, sb.w)) sup = 1;
            }
            int any = __syncthreads_or(sup);
            if (!any) {
                if (tid == 0) {
                    selbox[nsel] = cb;
                    selkey[nsel] = key;
                }
                nsel++;              // uniform across threads
                __syncthreads();     // publish selbox[nsel-1] before next cand
                if (nsel >= MAXOUT) break;
            }
        }
        __syncthreads();  // before restaging bbuf
    }

    // ---- phase 4: emit 400 rows [class, conf, x1,y1,x2,y2, extra] ----
    float* out0 = rows + (size_t)task * MAXOUT * 7;
    for (int r = tid; r < MAXOUT; r += 256) {
        float* o = out0 + (size_t)r * 7;
        if (r < nsel) {
            uint64_t key = selkey[r];
            uint32_t i = 0xFFFFFFFFu - (uint32_t)key;
            float sc = __uint_as_float((uint32_t)(key >> 32));
            float4 bx = selbox[r];
            o[0] = (float)(cm1 + 1);
            o[1] = sc;
            o[2] = bx.x;
            o[3] = bx.y;
            o[4] = bx.z;
            o[5] = bx.w;
            o[6] = img[(size_t)i * LASTD + (LASTD - 1)];
        } else {
            #pragma unroll
            for (int q = 0; q < 7; ++q) o[q] = 0.0f;
        }
    }
}

// One block per image: top-200 by conf (desc, flat-index asc on ties) over the
// 20*400 rows, matching jax.lax.top_k semantics exactly.
__global__ __launch_bounds__(256) void topk_per_image(const float* __restrict__ rows,
                                                      float* __restrict__ out) {
    __shared__ uint64_t keys[SORTN];  // 64 KiB
    const int b = blockIdx.x;
    const int tid = threadIdx.x;
    const float* rb = rows + (size_t)b * (NCM1 * MAXOUT) * 7;

    for (int f = tid; f < SORTN; f += 256) {
        uint64_t k = 0;
        if (f < NCM1 * MAXOUT) {
            float conf = rb[(size_t)f * 7 + 1];
            k = ((uint64_t)__float_as_uint(conf) << 32) |
                (uint32_t)(0xFFFFFFFFu - (uint32_t)f);
        }
        keys[f] = k;
    }
    __syncthreads();

    bitonic_sort_desc(keys, tid);

    if (tid < TOPK) {
        uint64_t key = keys[tid];
        uint32_t f = 0xFFFFFFFFu - (uint32_t)key;
        const float* src = rb + (size_t)f * 7;
        float* o = out + ((size_t)b * TOPK + tid) * 7;
        #pragma unroll
        for (int q = 0; q < 7; ++q) o[q] = src[q];
    }
}

extern "C" void kernel_launch(void* const* d_in, const int* in_sizes, int n_in,
                              void* d_out, int out_size, void* d_ws, size_t ws_size,
                              hipStream_t stream) {
    const float* yp = (const float*)d_in[0];
    float* rows = (float*)d_ws;  // NB*NCM1*MAXOUT*7 floats = 1.792 MB scratch
    float* out = (float*)d_out;

    hipLaunchKernelGGL(nms_per_class, dim3(NTASK), dim3(256), 0, stream, yp, rows);
    hipLaunchKernelGGL(topk_per_image, dim3(NB), dim3(256), 0, stream, rows, out);
}

// Round 2
// 268.394 us; speedup vs baseline: 4.3374x; 4.3374x over previous
//
#include <hip/hip_runtime.h>
#include <cstdint>

#define NB 8
#define NBOX 8732
#define NCL 21
#define NCM1 20
#define LASTD 102
#define CONF_TH 0.5f
#define IOU_TH 0.45f
#define TOPK 200
#define MAXOUT 400
#define SORTN 8192
#define NTASK (NB * NCM1)
#define THREADS 1024
#define NW 16  // waves per block

// IoU with explicit round-to-nearest ops (no FMA contraction) to match the
// host-side numpy/jax fp32 reference bit-for-bit. Strict > comparisons.
__device__ __forceinline__ bool iou_gt(float ax, float ay, float az, float aw,
                                       float bx, float by, float bz, float bw) {
    float x1 = fmaxf(ax, bx);
    float y1 = fmaxf(ay, by);
    float x2 = fminf(az, bz);
    float y2 = fminf(aw, bw);
    float iw = fmaxf(__fsub_rn(x2, x1), 0.0f);
    float ih = fmaxf(__fsub_rn(y2, y1), 0.0f);
    float inter = __fmul_rn(iw, ih);
    float aa = __fmul_rn(__fsub_rn(az, ax), __fsub_rn(aw, ay));
    float ab = __fmul_rn(__fsub_rn(bz, bx), __fsub_rn(bw, by));
    float uni = __fsub_rn(__fadd_rn(aa, ab), inter);
    if (!(uni > 0.0f)) return false;
    return __fdiv_rn(inter, uni) > IOU_TH;
}

__device__ __forceinline__ uint64_t shfl_xor_u64(uint64_t v, int m) {
    return (uint64_t)__shfl_xor((unsigned long long)v, m, 64);
}

// Descending bitonic sort of SORTN u64 keys in LDS. 1024 threads, 8 elems/thr.
// Element idx = e*1024 + tid, so idx^j for j<=32 is lane^j of the same wave:
// all j<=32 stages run in registers via shfl (no LDS, no barriers). Only the
// 28 j>=64 passes touch LDS. Caller must __syncthreads() before calling.
__device__ void bitonic_sort_desc(uint64_t* keys, int tid) {
    uint64_t v[8];
    // ---- k = 2..64: entirely wave-local, one LDS round-trip ----
    #pragma unroll
    for (int e = 0; e < 8; ++e) v[e] = keys[e * THREADS + tid];
    for (int k = 2; k <= 64; k <<= 1) {
        for (int j = k >> 1; j >= 1; j >>= 1) {
            #pragma unroll
            for (int e = 0; e < 8; ++e) {
                int idx = e * THREADS + tid;
                uint64_t p = shfl_xor_u64(v[e], j);
                bool takemax = (((idx & k) == 0) == ((idx & j) == 0));
                uint64_t mx = v[e] > p ? v[e] : p;
                uint64_t mn = v[e] > p ? p : v[e];
                v[e] = takemax ? mx : mn;
            }
        }
    }
    #pragma unroll
    for (int e = 0; e < 8; ++e) keys[e * THREADS + tid] = v[e];
    __syncthreads();
    // ---- k = 128..8192: LDS passes for j>=64, register tail for j<=32 ----
    for (int k = 128; k <= SORTN; k <<= 1) {
        for (int j = k >> 1; j >= 64; j >>= 1) {
            for (int t = tid; t < SORTN; t += THREADS) {
                int ixj = t ^ j;
                if (ixj > t) {
                    uint64_t a = keys[t];
                    uint64_t c = keys[ixj];
                    bool up = ((t & k) == 0);
                    if (up ? (a < c) : (a > c)) {
                        keys[t] = c;
                        keys[ixj] = a;
                    }
                }
            }
            __syncthreads();
        }
        #pragma unroll
        for (int e = 0; e < 8; ++e) v[e] = keys[e * THREADS + tid];
        for (int j = 32; j >= 1; j >>= 1) {
            #pragma unroll
            for (int e = 0; e < 8; ++e) {
                int idx = e * THREADS + tid;
                uint64_t p = shfl_xor_u64(v[e], j);
                bool takemax = (((idx & k) == 0) == ((idx & j) == 0));
                uint64_t mx = v[e] > p ? v[e] : p;
                uint64_t mn = v[e] > p ? p : v[e];
                v[e] = takemax ? mx : mn;
            }
        }
        #pragma unroll
        for (int e = 0; e < 8; ++e) keys[e * THREADS + tid] = v[e];
        __syncthreads();
    }
}

// One block per (image, class): compact conf>0.5, sort by (score desc, idx
// asc), batched greedy NMS (64 candidates/batch, 2.5 barriers/batch), emit
// 400 rows (zeros past nsel). Exactly replicates the reference scan order.
__global__ __launch_bounds__(THREADS) void nms_per_class(const float* __restrict__ yp,
                                                         float* __restrict__ rows) {
    __shared__ uint64_t keys[SORTN];         // 64 KiB
    __shared__ float4 cbox[64];              // batch candidate boxes
    __shared__ float4 selbox[MAXOUT];        // accepted boxes
    __shared__ uint64_t selkey[MAXOUT];      // accepted keys
    __shared__ uint64_t imask[NW][64];       // per-wave intra-batch masks
    __shared__ unsigned long long supAll;    // OR of ext-suppression ballots
    __shared__ int wsum[NW];
    __shared__ int nselshare, doneflag;

    const int task = blockIdx.x;
    const int b = task / NCM1;
    const int cm1 = task % NCM1;
    const int tid = threadIdx.x;
    const int lane = tid & 63;
    const int wav = tid >> 6;
    const float* img = yp + (size_t)b * NBOX * LASTD;
    const int boxoff = NCL + 4 * cm1;

    // ---- phase 1: order-preserving compaction of conf>0.5 candidates ----
    int M = 0;
    for (int it = 0; it < (NBOX + THREADS - 1) / THREADS; ++it) {
        int i = it * THREADS + tid;
        float conf = 0.0f;
        bool pred = false;
        if (i < NBOX) {
            conf = img[(size_t)i * LASTD + (1 + cm1)];
            pred = conf > CONF_TH;
        }
        unsigned long long bal = __ballot(pred);
        int before = __popcll(bal & ((1ull << lane) - 1ull));
        if (lane == 0) wsum[wav] = __popcll(bal);
        __syncthreads();
        int wbase = 0, total = 0;
        #pragma unroll
        for (int w = 0; w < NW; ++w) {
            if (w < wav) wbase += wsum[w];
            total += wsum[w];
        }
        if (pred) {
            int pos = M + wbase + before;
            if (pos < SORTN)
                keys[pos] = ((uint64_t)__float_as_uint(conf) << 32) |
                            (uint32_t)(0xFFFFFFFFu - (uint32_t)i);
        }
        M += total;
        __syncthreads();
    }
    if (M > SORTN) M = SORTN;
    for (int m = M + tid; m < SORTN; m += THREADS) keys[m] = 0;  // sentinel pad
    if (tid == 0) supAll = 0ull;
    __syncthreads();

    // ---- phase 2: sort (score desc, original idx asc) ----
    bitonic_sort_desc(keys, tid);

    // ---- phase 3: batched greedy scan ----
    int nsel = 0;
    bool done = false;
    for (int cb0 = 0; cb0 < SORTN && !done; cb0 += 64) {
        // Phase A (all waves): own candidate, ext-suppression vs accepted list
        uint64_t mykey = keys[cb0 + lane];
        bool valid = (mykey >> 32) != 0;
        float4 mybox = make_float4(0.f, 0.f, 0.f, 0.f);
        if (valid) {
            uint32_t i = 0xFFFFFFFFu - (uint32_t)mykey;
            const float* bp = img + (size_t)i * LASTD + boxoff;
            mybox = make_float4(bp[0], bp[1], bp[2], bp[3]);
        }
        if (wav == 0) cbox[lane] = mybox;
        bool sup = false;
        if (valid) {
            for (int j = wav; j < nsel; j += NW) {
                float4 sb = selbox[j];
                if (iou_gt(mybox.x, mybox.y, mybox.z, mybox.w,
                           sb.x, sb.y, sb.z, sb.w)) sup = true;
            }
        }
        unsigned long long bal = __ballot(sup);
        if (lane == 0 && bal) atomicOr(&supAll, bal);
        __syncthreads();  // barrier 1: supAll + cbox complete

        // Phase B (all waves): split intra-batch pairwise IoU
        unsigned long long E = supAll;       // uniform read (pre-zeroing)
        unsigned long long V = __ballot(valid);
        unsigned long long dead0 = E | ~V;
        uint64_t im = 0;
        for (int t = wav; t < 64; t += NW) {
            if ((dead0 >> t) & 1ull) continue;   // dead can never suppress
            float4 tb = cbox[t];
            if (valid && t < lane &&
                iou_gt(mybox.x, mybox.y, mybox.z, mybox.w,
                       tb.x, tb.y, tb.z, tb.w)) im |= (1ull << t);
        }
        imask[wav][lane] = im;
        __syncthreads();  // barrier 1.5: imask visible, supAll reads done

        // Phase C (wave 0): sequential greedy resolve via 64-bit masks
        if (wav == 0) {
            if (lane == 0) supAll = 0ull;  // safe: all reads were pre-b1.5
            uint64_t imf = 0;
            #pragma unroll
            for (int w = 0; w < NW; ++w) imf |= imask[w][lane];
            uint64_t alive = ~dead0;
            uint64_t accm = 0;
            int cnt = nsel;
            while (alive != 0ull && cnt < MAXOUT) {
                int t = __ffsll((unsigned long long)alive) - 1;
                alive &= alive - 1;          // clear bit t
                accm |= (1ull << t);
                cnt++;
                unsigned long long supt = __ballot((imf >> t) & 1ull);
                alive &= ~supt;
            }
            if ((accm >> lane) & 1ull) {
                int pos = nsel + __popcll(accm & ((1ull << lane) - 1ull));
                selbox[pos] = mybox;
                selkey[pos] = mykey;
            }
            if (lane == 0) {
                nselshare = cnt;
                doneflag = (cnt >= MAXOUT) || (V != ~0ull);
            }
        }
        __syncthreads();  // barrier 2: appended boxes + nsel published
        nsel = nselshare;
        done = (doneflag != 0);
    }

    // ---- phase 4: emit 400 rows [class, conf, x1,y1,x2,y2, extra] ----
    float* out0 = rows + (size_t)task * MAXOUT * 7;
    for (int r = tid; r < MAXOUT; r += THREADS) {
        float* o = out0 + (size_t)r * 7;
        if (r < nsel) {
            uint64_t key = selkey[r];
            uint32_t i = 0xFFFFFFFFu - (uint32_t)key;
            float sc = __uint_as_float((uint32_t)(key >> 32));
            float4 bx = selbox[r];
            o[0] = (float)(cm1 + 1);
            o[1] = sc;
            o[2] = bx.x;
            o[3] = bx.y;
            o[4] = bx.z;
            o[5] = bx.w;
            o[6] = img[(size_t)i * LASTD + (LASTD - 1)];
        } else {
            #pragma unroll
            for (int q = 0; q < 7; ++q) o[q] = 0.0f;
        }
    }
}

// One block per image: top-200 by conf (desc, flat-index asc on ties) over the
// 20*400 rows, matching jax.lax.top_k semantics exactly.
__global__ __launch_bounds__(THREADS) void topk_per_image(const float* __restrict__ rows,
                                                          float* __restrict__ out) {
    __shared__ uint64_t keys[SORTN];  // 64 KiB
    const int b = blockIdx.x;
    const int tid = threadIdx.x;
    const float* rb = rows + (size_t)b * (NCM1 * MAXOUT) * 7;

    for (int f = tid; f < SORTN; f += THREADS) {
        uint64_t k = 0;
        if (f < NCM1 * MAXOUT) {
            float conf = rb[(size_t)f * 7 + 1];
            k = ((uint64_t)__float_as_uint(conf) << 32) |
                (uint32_t)(0xFFFFFFFFu - (uint32_t)f);
        }
        keys[f] = k;
    }
    __syncthreads();

    bitonic_sort_desc(keys, tid);

    if (tid < TOPK) {
        uint64_t key = keys[tid];
        uint32_t f = 0xFFFFFFFFu - (uint32_t)key;
        const float* src = rb + (size_t)f * 7;
        float* o = out + ((size_t)b * TOPK + tid) * 7;
        #pragma unroll
        for (int q = 0; q < 7; ++q) o[q] = src[q];
    }
}

extern "C" void kernel_launch(void* const* d_in, const int* in_sizes, int n_in,
                              void* d_out, int out_size, void* d_ws, size_t ws_size,
                              hipStream_t stream) {
    const float* yp = (const float*)d_in[0];
    float* rows = (float*)d_ws;  // NB*NCM1*MAXOUT*7 floats = 1.792 MB scratch
    float* out = (float*)d_out;

    hipLaunchKernelGGL(nms_per_class, dim3(NTASK), dim3(THREADS), 0, stream, yp, rows);
    hipLaunchKernelGGL(topk_per_image, dim3(NB), dim3(THREADS), 0, stream, rows, out);
}

// Round 3
// 126.368 us; speedup vs baseline: 9.2122x; 2.1239x over previous
//
#include <hip/hip_runtime.h>
#include <cstdint>

#define NB 8
#define NBOX 8732
#define NCL 21
#define NCM1 20
#define LASTD 102
#define CONF_TH 0.5f
#define HI_TH 0.85f
#define IOU_TH 0.45f
#define TOPK 200
#define MAXOUT 400
#define SN_FAST 2048
#define SN_FULL 8192
#define NTASK (NB * NCM1)
#define THREADS 1024
#define NW 16
#define NIT ((NBOX + THREADS - 1) / THREADS)  // 9

struct SM {
    float4 selbox[MAXOUT];                 // 6.4 KB (16B aligned, first)
    uint64_t keys[SN_FULL];                // 64 KB
    uint64_t selkey[MAXOUT];               // 3.2 KB
    uint64_t imask[NW][64];                // 8 KB
    unsigned long long supAll;
    int wsum2[NIT][NW];
    int mlo;
    int nselshare, doneflag;
};

// IoU with explicit round-to-nearest ops (no FMA contraction) to match the
// host-side fp32 reference bit-for-bit. Strict > comparisons.
__device__ __forceinline__ bool iou_gt(float ax, float ay, float az, float aw,
                                       float bx, float by, float bz, float bw) {
    float x1 = fmaxf(ax, bx);
    float y1 = fmaxf(ay, by);
    float x2 = fminf(az, bz);
    float y2 = fminf(aw, bw);
    float iw = fmaxf(__fsub_rn(x2, x1), 0.0f);
    float ih = fmaxf(__fsub_rn(y2, y1), 0.0f);
    float inter = __fmul_rn(iw, ih);
    float aa = __fmul_rn(__fsub_rn(az, ax), __fsub_rn(aw, ay));
    float ab = __fmul_rn(__fsub_rn(bz, bx), __fsub_rn(bw, by));
    float uni = __fsub_rn(__fadd_rn(aa, ab), inter);
    if (!(uni > 0.0f)) return false;
    return __fdiv_rn(inter, uni) > IOU_TH;
}

__device__ __forceinline__ uint64_t shfl_xor_u64(uint64_t v, int m) {
    return (uint64_t)__shfl_xor((unsigned long long)v, m, 64);
}

// Descending bitonic sort of SN u64 keys in LDS. 1024 threads, SN/1024 elems
// per thread. j<=32 stages run in registers via shfl; only j>=64 passes touch
// LDS. Caller must __syncthreads() before calling.
template <int SN>
__device__ void bitonic_sort_desc(uint64_t* keys, int tid) {
    constexpr int E = SN / THREADS;
    uint64_t v[E];
    #pragma unroll
    for (int e = 0; e < E; ++e) v[e] = keys[e * THREADS + tid];
    for (int k = 2; k <= 64; k <<= 1) {
        for (int j = k >> 1; j >= 1; j >>= 1) {
            #pragma unroll
            for (int e = 0; e < E; ++e) {
                int idx = e * THREADS + tid;
                uint64_t p = shfl_xor_u64(v[e], j);
                bool takemax = (((idx & k) == 0) == ((idx & j) == 0));
                uint64_t mx = v[e] > p ? v[e] : p;
                uint64_t mn = v[e] > p ? p : v[e];
                v[e] = takemax ? mx : mn;
            }
        }
    }
    #pragma unroll
    for (int e = 0; e < E; ++e) keys[e * THREADS + tid] = v[e];
    __syncthreads();
    for (int k = 128; k <= SN; k <<= 1) {
        for (int j = k >> 1; j >= 64; j >>= 1) {
            for (int t = tid; t < SN; t += THREADS) {
                int ixj = t ^ j;
                if (ixj > t) {
                    uint64_t a = keys[t];
                    uint64_t c = keys[ixj];
                    bool up = ((t & k) == 0);
                    if (up ? (a < c) : (a > c)) {
                        keys[t] = c;
                        keys[ixj] = a;
                    }
                }
            }
            __syncthreads();
        }
        #pragma unroll
        for (int e = 0; e < E; ++e) v[e] = keys[e * THREADS + tid];
        for (int j = 32; j >= 1; j >>= 1) {
            #pragma unroll
            for (int e = 0; e < E; ++e) {
                int idx = e * THREADS + tid;
                uint64_t p = shfl_xor_u64(v[e], j);
                bool takemax = (((idx & k) == 0) == ((idx & j) == 0));
                uint64_t mx = v[e] > p ? v[e] : p;
                uint64_t mn = v[e] > p ? p : v[e];
                v[e] = takemax ? mx : mn;
            }
        }
        #pragma unroll
        for (int e = 0; e < E; ++e) keys[e * THREADS + tid] = v[e];
        __syncthreads();
    }
}

// Order-preserving compaction of conf>thr candidates into sm->keys[0..SN).
// All NIT loads issued up front (overlapped latency); 2 barriers total.
// Mout = total count of conf>thr (may exceed SN); MloOut = count in (0.5,thr].
template <int SN>
__device__ void compact(const float* __restrict__ img, int cm1, float thr,
                        SM* sm, int tid, int lane, int wav,
                        int& Mout, int& MloOut) {
    float confs[NIT];
    #pragma unroll
    for (int it = 0; it < NIT; ++it) {
        int i = it * THREADS + tid;
        confs[it] = (i < NBOX) ? img[(size_t)i * LASTD + (1 + cm1)] : 0.0f;
    }
    if (tid == 0) { sm->mlo = 0; sm->supAll = 0ull; }
    __syncthreads();
    bool pred[NIT];
    int before[NIT];
    #pragma unroll
    for (int it = 0; it < NIT; ++it) {
        int i = it * THREADS + tid;
        float c = confs[it];
        pred[it] = (i < NBOX) && (c > thr);
        bool lo = (i < NBOX) && (c > CONF_TH) && !(c > thr);
        unsigned long long bal = __ballot(pred[it]);
        before[it] = __popcll(bal & ((1ull << lane) - 1ull));
        if (lane == 0) sm->wsum2[it][wav] = __popcll(bal);
        unsigned long long bal2 = __ballot(lo);
        if (lane == 0 && bal2) atomicAdd(&sm->mlo, __popcll(bal2));
    }
    __syncthreads();
    int run = 0;
    int base[NIT];
    #pragma unroll
    for (int it = 0; it < NIT; ++it) {
        int wb = run;
        for (int w = 0; w < NW; ++w) {
            int c = sm->wsum2[it][w];
            if (w < wav) wb += c;
            run += c;
        }
        base[it] = wb;
    }
    #pragma unroll
    for (int it = 0; it < NIT; ++it) {
        if (pred[it]) {
            int pos = base[it] + before[it];
            int i = it * THREADS + tid;
            if (pos < SN)
                sm->keys[pos] = ((uint64_t)__float_as_uint(confs[it]) << 32) |
                                (uint32_t)(0xFFFFFFFFu - (uint32_t)i);
        }
    }
    for (int m = run + tid; m < SN; m += THREADS) sm->keys[m] = 0;
    __syncthreads();
    Mout = run;
    MloOut = sm->mlo;
}

// Batched greedy scan over the sorted keys: 64 candidates/batch, 2 barriers
// per batch. Exactly replicates the reference's 400-step argmax+suppress scan.
template <int SN>
__device__ int scan(const float* __restrict__ img, int boxoff, SM* sm,
                    int tid, int lane, int wav) {
    int nsel = 0;
    bool done = false;
    for (int cb0 = 0; cb0 < SN && !done; cb0 += 64) {
        uint64_t mykey = sm->keys[cb0 + lane];
        bool valid = (mykey >> 32) != 0;
        float4 mybox = make_float4(0.f, 0.f, 0.f, 0.f);
        if (valid) {
            uint32_t i = 0xFFFFFFFFu - (uint32_t)mykey;
            const float* bp = img + (size_t)i * LASTD + boxoff;
            mybox = make_float4(bp[0], bp[1], bp[2], bp[3]);
        }
        // ext-suppression vs accepted list (waves split the j range)
        bool sup = false;
        for (int j = wav; j < nsel; j += NW) {
            float4 sb = sm->selbox[j];
            if (iou_gt(mybox.x, mybox.y, mybox.z, mybox.w,
                       sb.x, sb.y, sb.z, sb.w)) sup = true;
        }
        unsigned long long bal = __ballot(sup);
        if (lane == 0 && bal) atomicOr(&sm->supAll, bal);
        // intra-batch pairwise IoU; candidate boxes fetched via shfl
        uint64_t im = 0;
        #pragma unroll
        for (int tt = 0; tt < 4; ++tt) {
            int t = wav + tt * NW;
            float tx = __shfl(mybox.x, t);
            float ty = __shfl(mybox.y, t);
            float tz = __shfl(mybox.z, t);
            float tw = __shfl(mybox.w, t);
            if (valid && t < lane &&
                iou_gt(mybox.x, mybox.y, mybox.z, mybox.w, tx, ty, tz, tw))
                im |= (1ull << t);
        }
        sm->imask[wav][lane] = im;
        unsigned long long V = __ballot(valid);
        __syncthreads();  // barrier 1: supAll + imask published
        if (wav == 0) {
            unsigned long long E = sm->supAll;
            if (lane == 0) sm->supAll = 0ull;
            uint64_t imf = 0;
            #pragma unroll
            for (int w = 0; w < NW; ++w) imf |= sm->imask[w][lane];
            uint64_t dead0 = E | ~V;
            uint64_t alive = ~dead0;
            uint64_t accm = 0;
            int cnt = nsel;
            while (alive != 0ull && cnt < MAXOUT) {
                int t = __ffsll((unsigned long long)alive) - 1;
                alive &= alive - 1;
                accm |= (1ull << t);
                cnt++;
                unsigned long long supt = __ballot((imf >> t) & 1ull);
                alive &= ~supt;
            }
            if ((accm >> lane) & 1ull) {
                int pos = nsel + __popcll(accm & ((1ull << lane) - 1ull));
                sm->selbox[pos] = mybox;
                sm->selkey[pos] = mykey;
            }
            if (lane == 0) {
                sm->nselshare = cnt;
                sm->doneflag = (cnt >= MAXOUT) || (V != ~0ull);
            }
        }
        __syncthreads();  // barrier 2: accepted boxes + nsel published
        nsel = sm->nselshare;
        done = sm->doneflag != 0;
    }
    return nsel;
}

// One block per (image, class). Fast path: sort only conf>0.85 (<=2048) and
// scan; exact whenever 400 accepts are reached or no lower candidates exist.
// Otherwise fall back to the full conf>0.5 / 8192-sort path (round-2 exact).
__global__ __launch_bounds__(THREADS) void nms_per_class(const float* __restrict__ yp,
                                                         float* __restrict__ rows) {
    __shared__ SM sm;
    const int task = blockIdx.x;
    const int b = task / NCM1;
    const int cm1 = task % NCM1;
    const int tid = threadIdx.x;
    const int lane = tid & 63;
    const int wav = tid >> 6;
    const float* img = yp + (size_t)b * NBOX * LASTD;
    const int boxoff = NCL + 4 * cm1;

    int Mhi, Mlo;
    compact<SN_FAST>(img, cm1, HI_TH, &sm, tid, lane, wav, Mhi, Mlo);
    int nsel = -1;
    if (Mhi <= SN_FAST) {
        bitonic_sort_desc<SN_FAST>(sm.keys, tid);
        nsel = scan<SN_FAST>(img, boxoff, &sm, tid, lane, wav);
        if (nsel < MAXOUT && Mlo > 0) nsel = -1;  // needs lower candidates
    }
    if (nsel < 0) {
        int M2, Ml2;
        compact<SN_FULL>(img, cm1, CONF_TH, &sm, tid, lane, wav, M2, Ml2);
        bitonic_sort_desc<SN_FULL>(sm.keys, tid);
        nsel = scan<SN_FULL>(img, boxoff, &sm, tid, lane, wav);
    }

    // emit 400 rows [class, conf, x1,y1,x2,y2, extra], zeros past nsel
    float* out0 = rows + (size_t)task * MAXOUT * 7;
    for (int r = tid; r < MAXOUT; r += THREADS) {
        float* o = out0 + (size_t)r * 7;
        if (r < nsel) {
            uint64_t key = sm.selkey[r];
            uint32_t i = 0xFFFFFFFFu - (uint32_t)key;
            float sc = __uint_as_float((uint32_t)(key >> 32));
            float4 bx = sm.selbox[r];
            o[0] = (float)(cm1 + 1);
            o[1] = sc;
            o[2] = bx.x;
            o[3] = bx.y;
            o[4] = bx.z;
            o[5] = bx.w;
            o[6] = img[(size_t)i * LASTD + (LASTD - 1)];
        } else {
            #pragma unroll
            for (int q = 0; q < 7; ++q) o[q] = 0.0f;
        }
    }
}

// One block per image: top-200 by (conf desc, flat idx asc) over 20*400 rows.
// Per-class lists are already sorted desc; top-200 never needs within-class
// rank >= 256, so: 32 lists x 256 keys, 5 rounds of pairwise bitonic top-256
// merges (max-combine + 8 merge stages), then gather the first 200 rows.
__global__ __launch_bounds__(THREADS) void topk_per_image(const float* __restrict__ rows,
                                                          float* __restrict__ out) {
    __shared__ uint64_t K[8192];
    const int b = blockIdx.x;
    const int tid = threadIdx.x;
    const float* rb = rows + (size_t)b * (NCM1 * MAXOUT) * 7;

    for (int x = tid; x < 8192; x += THREADS) {
        int list = x >> 8, r = x & 255;
        uint64_t k = 0;
        if (list < NCM1) {
            int flat = list * MAXOUT + r;
            float conf = rb[(size_t)flat * 7 + 1];
            k = ((uint64_t)__float_as_uint(conf) << 32) |
                (uint32_t)(0xFFFFFFFFu - (uint32_t)flat);
        }
        K[x] = k;
    }
    __syncthreads();

    for (int round = 0; round < 5; ++round) {
        int npairs = 16 >> round;
        int sep = 256 << round;
        // max-combine: A[t] = max(A[t], B[255-t]) -> bitonic top-256
        for (int w = tid; w < npairs * 256; w += THREADS) {
            int p = w >> 8, t = w & 255;
            int A = p * 2 * sep;
            uint64_t a = K[A + t];
            uint64_t c = K[A + sep + 255 - t];
            K[A + t] = a > c ? a : c;
        }
        __syncthreads();
        // bitonic merge desc of each 256-length result
        for (int j = 128; j >= 1; j >>= 1) {
            for (int w = tid; w < npairs * 128; w += THREADS) {
                int p = w >> 7, q = w & 127;
                int t = ((q & ~(j - 1)) << 1) | (q & (j - 1));
                int A = p * 2 * sep;
                uint64_t x0 = K[A + t];
                uint64_t x1 = K[A + t + j];
                if (x0 < x1) {
                    K[A + t] = x1;
                    K[A + t + j] = x0;
                }
            }
            __syncthreads();
        }
    }

    if (tid < TOPK) {
        uint64_t key = K[tid];
        uint32_t flat = 0xFFFFFFFFu - (uint32_t)key;
        const float* src = rb + (size_t)flat * 7;
        float* o = out + ((size_t)b * TOPK + tid) * 7;
        #pragma unroll
        for (int q = 0; q < 7; ++q) o[q] = src[q];
    }
}

extern "C" void kernel_launch(void* const* d_in, const int* in_sizes, int n_in,
                              void* d_out, int out_size, void* d_ws, size_t ws_size,
                              hipStream_t stream) {
    const float* yp = (const float*)d_in[0];
    float* rows = (float*)d_ws;  // NB*NCM1*MAXOUT*7 floats = 1.792 MB scratch
    float* out = (float*)d_out;

    hipLaunchKernelGGL(nms_per_class, dim3(NTASK), dim3(THREADS), 0, stream, yp, rows);
    hipLaunchKernelGGL(topk_per_image, dim3(NB), dim3(THREADS), 0, stream, rows, out);
}

// Round 4
// 105.671 us; speedup vs baseline: 11.0166x; 1.1959x over previous
//
#include <hip/hip_runtime.h>
#include <cstdint>

#define NB 8
#define NBOX 8732
#define NCL 21
#define NCM1 20
#define LASTD 102
#define CONF_TH 0.5f
#define IOU_TH 0.45f
#define TOPK 200
#define MAXOUT 400
#define NTASK (NB * NCM1)
#define THREADS 1024
#define NW 16
#define NIT ((NBOX + THREADS - 1) / THREADS)  // 9
#define NBIN 1024
#define KPAD 8768  // 64*137 >= NBOX: counting-sorted keys always fit; no fallback

struct SM {
    float4 selbox[MAXOUT];       // 6.4 KB
    uint64_t keys[KPAD];         // 70.1 KB
    uint64_t selkey[MAXOUT];     // 3.2 KB
    uint64_t imask[NW][64];      // 8 KB
    int hist[NBIN];              // 4 KB (histogram, then scatter counter/bin count)
    int binstart[NBIN];          // 4 KB
    int wavetot[NW];
    unsigned long long supAll;
    int Mshare, nselshare, doneflag;
};

// IoU with explicit round-to-nearest ops (no FMA contraction) to match the
// host-side fp32 reference bit-for-bit. Strict > comparisons.
__device__ __forceinline__ bool iou_gt(float ax, float ay, float az, float aw,
                                       float bx, float by, float bz, float bw) {
    float x1 = fmaxf(ax, bx);
    float y1 = fmaxf(ay, by);
    float x2 = fminf(az, bz);
    float y2 = fminf(aw, bw);
    float iw = fmaxf(__fsub_rn(x2, x1), 0.0f);
    float ih = fmaxf(__fsub_rn(y2, y1), 0.0f);
    float inter = __fmul_rn(iw, ih);
    float aa = __fmul_rn(__fsub_rn(az, ax), __fsub_rn(aw, ay));
    float ab = __fmul_rn(__fsub_rn(bz, bx), __fsub_rn(bw, by));
    float uni = __fsub_rn(__fadd_rn(aa, ab), inter);
    if (!(uni > 0.0f)) return false;
    return __fdiv_rn(inter, uni) > IOU_TH;
}

__device__ __forceinline__ float4 load_box(const float* __restrict__ img,
                                           int boxoff, uint64_t key) {
    if ((key >> 32) == 0) return make_float4(0.f, 0.f, 0.f, 0.f);
    uint32_t i = 0xFFFFFFFFu - (uint32_t)key;
    const float* bp = img + (size_t)i * LASTD + boxoff;
    return make_float4(bp[0], bp[1], bp[2], bp[3]);
}

// One block per (image, class): counting-sort ALL conf>0.5 candidates into
// exact descending (score, idx-asc) order, then batched greedy NMS scan that
// exactly replicates the reference's 400-step argmax+suppress loop.
__global__ __launch_bounds__(THREADS) void nms_per_class(const float* __restrict__ yp,
                                                         float* __restrict__ rows) {
    __shared__ SM sm;
    const int task = blockIdx.x;
    const int b = task / NCM1;
    const int cm1 = task % NCM1;
    const int tid = threadIdx.x;
    const int lane = tid & 63;
    const int wav = tid >> 6;
    const float* img = yp + (size_t)b * NBOX * LASTD;
    const int boxoff = NCL + 4 * cm1;

    // ---- phase 1: load conf column (9 strided loads, all in flight) ----
    float confs[NIT];
    #pragma unroll
    for (int it = 0; it < NIT; ++it) {
        int i = it * THREADS + tid;
        confs[it] = (i < NBOX) ? img[(size_t)i * LASTD + (1 + cm1)] : 0.0f;
    }
    sm.hist[tid] = 0;
    if (tid == 0) sm.supAll = 0ull;
    __syncthreads();

    // ---- phase 2: histogram over high 10 mantissa bits (scores in (0.5,1)) ----
    #pragma unroll
    for (int it = 0; it < NIT; ++it) {
        int i = it * THREADS + tid;
        if (i < NBOX && confs[it] > CONF_TH) {
            int bin = (int)((__float_as_uint(confs[it]) - 0x3F000000u) >> 13);
            atomicAdd(&sm.hist[bin], 1);
        }
    }
    __syncthreads();

    // ---- phase 3: descending bin bases via suffix-sum (wave shfl + cross) ----
    int x = sm.hist[tid];
    int s = x;
    #pragma unroll
    for (int d = 1; d <= 32; d <<= 1) {
        int y = __shfl_down(s, d);
        if (lane + d < 64) s += y;
    }
    if (lane == 0) sm.wavetot[wav] = s;
    __syncthreads();
    int cross = 0;
    #pragma unroll
    for (int w = 0; w < NW; ++w)
        if (w > wav) cross += sm.wavetot[w];
    int base = cross + s - x;        // #keys in bins strictly above mine
    sm.binstart[tid] = base;
    if (tid == 0) sm.Mshare = cross + s;  // total candidate count
    sm.hist[tid] = 0;                // reuse as scatter counter
    __syncthreads();

    // ---- phase 4: scatter keys to bin regions (arbitrary order within bin) ----
    #pragma unroll
    for (int it = 0; it < NIT; ++it) {
        int i = it * THREADS + tid;
        if (i < NBOX && confs[it] > CONF_TH) {
            uint32_t bits = __float_as_uint(confs[it]);
            int bin = (int)((bits - 0x3F000000u) >> 13);
            int slot = sm.binstart[bin] + atomicAdd(&sm.hist[bin], 1);
            sm.keys[slot] = ((uint64_t)bits << 32) |
                            (uint32_t)(0xFFFFFFFFu - (uint32_t)i);
        }
    }
    __syncthreads();
    const int M = sm.Mshare;
    for (int m = M + tid; m < KPAD; m += THREADS) sm.keys[m] = 0;
    // ---- phase 5: per-bin insertion sort (thread tid owns bin tid, ~4 keys) --
    {
        int s0 = sm.binstart[tid], h = sm.hist[tid];
        for (int i2 = 1; i2 < h; ++i2) {
            uint64_t key = sm.keys[s0 + i2];
            int j = i2 - 1;
            while (j >= 0 && sm.keys[s0 + j] < key) {
                sm.keys[s0 + j + 1] = sm.keys[s0 + j];
                --j;
            }
            sm.keys[s0 + j + 1] = key;
        }
    }
    __syncthreads();

    // ---- phase 6: batched greedy scan, 64 cand/batch, next-batch prefetch ----
    int nsel = 0;
    bool done = false;
    uint64_t key_n = sm.keys[lane];
    float4 box_n = load_box(img, boxoff, key_n);
    for (int cb0 = 0; cb0 < KPAD && !done; cb0 += 64) {
        uint64_t mykey = key_n;
        float4 mybox = box_n;
        // prefetch next batch (keys are read-only during scan; hides gather)
        int nb0 = cb0 + 64;
        key_n = (nb0 < KPAD) ? sm.keys[nb0 + lane] : 0;
        box_n = load_box(img, boxoff, key_n);
        bool valid = (mykey >> 32) != 0;
        // ext-suppression vs accepted list (waves split the j range)
        bool sup = false;
        for (int j = wav; j < nsel; j += NW) {
            float4 sb = sm.selbox[j];
            if (iou_gt(mybox.x, mybox.y, mybox.z, mybox.w,
                       sb.x, sb.y, sb.z, sb.w)) sup = true;
        }
        unsigned long long bal = __ballot(sup);
        if (lane == 0 && bal) atomicOr(&sm.supAll, bal);
        // intra-batch pairwise IoU; candidate boxes fetched via shfl
        uint64_t im = 0;
        #pragma unroll
        for (int tt = 0; tt < 4; ++tt) {
            int t = wav + tt * NW;
            float tx = __shfl(mybox.x, t);
            float ty = __shfl(mybox.y, t);
            float tz = __shfl(mybox.z, t);
            float tw = __shfl(mybox.w, t);
            if (valid && t < lane &&
                iou_gt(mybox.x, mybox.y, mybox.z, mybox.w, tx, ty, tz, tw))
                im |= (1ull << t);
        }
        sm.imask[wav][lane] = im;
        unsigned long long V = __ballot(valid);
        __syncthreads();  // barrier 1: supAll + imask published
        if (wav == 0) {
            unsigned long long E = sm.supAll;
            if (lane == 0) sm.supAll = 0ull;
            uint64_t imf = 0;
            #pragma unroll
            for (int w = 0; w < NW; ++w) imf |= sm.imask[w][lane];
            uint64_t dead0 = E | ~V;
            uint64_t alive = ~dead0;
            uint64_t accm = 0;
            int cnt = nsel;
            while (alive != 0ull && cnt < MAXOUT) {
                int t = __ffsll((unsigned long long)alive) - 1;
                alive &= alive - 1;
                accm |= (1ull << t);
                cnt++;
                unsigned long long supt = __ballot((imf >> t) & 1ull);
                alive &= ~supt;
            }
            if ((accm >> lane) & 1ull) {
                int pos = nsel + __popcll(accm & ((1ull << lane) - 1ull));
                sm.selbox[pos] = mybox;
                sm.selkey[pos] = mykey;
            }
            if (lane == 0) {
                sm.nselshare = cnt;
                sm.doneflag = (cnt >= MAXOUT) || (V != ~0ull);
            }
        }
        __syncthreads();  // barrier 2: accepted boxes + nsel published
        nsel = sm.nselshare;
        done = sm.doneflag != 0;
    }

    // ---- phase 7: emit 400 rows [class, conf, x1,y1,x2,y2, extra] ----
    float* out0 = rows + (size_t)task * MAXOUT * 7;
    for (int r = tid; r < MAXOUT; r += THREADS) {
        float* o = out0 + (size_t)r * 7;
        if (r < nsel) {
            uint64_t key = sm.selkey[r];
            uint32_t i = 0xFFFFFFFFu - (uint32_t)key;
            float sc = __uint_as_float((uint32_t)(key >> 32));
            float4 bx = sm.selbox[r];
            o[0] = (float)(cm1 + 1);
            o[1] = sc;
            o[2] = bx.x;
            o[3] = bx.y;
            o[4] = bx.z;
            o[5] = bx.w;
            o[6] = img[(size_t)i * LASTD + (LASTD - 1)];
        } else {
            #pragma unroll
            for (int q = 0; q < 7; ++q) o[q] = 0.0f;
        }
    }
}

// One block per image: top-200 by (conf desc, flat idx asc) over 20*400 rows.
// Per-class lists are already sorted desc; top-200 never needs within-class
// rank >= 256, so: 32 lists x 256 keys, 5 rounds of pairwise bitonic top-256
// merges (max-combine + 8 merge stages), then gather the first 200 rows.
__global__ __launch_bounds__(THREADS) void topk_per_image(const float* __restrict__ rows,
                                                          float* __restrict__ out) {
    __shared__ uint64_t K[8192];
    const int b = blockIdx.x;
    const int tid = threadIdx.x;
    const float* rb = rows + (size_t)b * (NCM1 * MAXOUT) * 7;

    for (int x = tid; x < 8192; x += THREADS) {
        int list = x >> 8, r = x & 255;
        uint64_t k = 0;
        if (list < NCM1) {
            int flat = list * MAXOUT + r;
            float conf = rb[(size_t)flat * 7 + 1];
            k = ((uint64_t)__float_as_uint(conf) << 32) |
                (uint32_t)(0xFFFFFFFFu - (uint32_t)flat);
        }
        K[x] = k;
    }
    __syncthreads();

    for (int round = 0; round < 5; ++round) {
        int npairs = 16 >> round;
        int sep = 256 << round;
        for (int w = tid; w < npairs * 256; w += THREADS) {
            int p = w >> 8, t = w & 255;
            int A = p * 2 * sep;
            uint64_t a = K[A + t];
            uint64_t c = K[A + sep + 255 - t];
            K[A + t] = a > c ? a : c;
        }
        __syncthreads();
        for (int j = 128; j >= 1; j >>= 1) {
            for (int w = tid; w < npairs * 128; w += THREADS) {
                int p = w >> 7, q = w & 127;
                int t = ((q & ~(j - 1)) << 1) | (q & (j - 1));
                int A = p * 2 * sep;
                uint64_t x0 = K[A + t];
                uint64_t x1 = K[A + t + j];
                if (x0 < x1) {
                    K[A + t] = x1;
                    K[A + t + j] = x0;
                }
            }
            __syncthreads();
        }
    }

    if (tid < TOPK) {
        uint64_t key = K[tid];
        uint32_t flat = 0xFFFFFFFFu - (uint32_t)key;
        const float* src = rb + (size_t)flat * 7;
        float* o = out + ((size_t)b * TOPK + tid) * 7;
        #pragma unroll
        for (int q = 0; q < 7; ++q) o[q] = src[q];
    }
}

extern "C" void kernel_launch(void* const* d_in, const int* in_sizes, int n_in,
                              void* d_out, int out_size, void* d_ws, size_t ws_size,
                              hipStream_t stream) {
    const float* yp = (const float*)d_in[0];
    float* rows = (float*)d_ws;  // NB*NCM1*MAXOUT*7 floats = 1.792 MB scratch
    float* out = (float*)d_out;

    hipLaunchKernelGGL(nms_per_class, dim3(NTASK), dim3(THREADS), 0, stream, yp, rows);
    hipLaunchKernelGGL(topk_per_image, dim3(NB), dim3(THREADS), 0, stream, rows, out);
}